// Round 15
// baseline (230.375 us; speedup 1.0000x reference)
//
#include <hip/hip_runtime.h>
#include <hip/hip_bf16.h>

typedef unsigned short u16;
typedef __bf16 bf16x8 __attribute__((ext_vector_type(8)));
typedef float f32x4 __attribute__((ext_vector_type(4)));

#define L_SEQ 4096
#define CDIM  1024
#define NH    16
#define HD    64
#define N_QKV 3072
// LDS row stride (halfwords). 72 hw = 144 B: 16-B aligned rows; 36 dw = 4 mod 32
// -> 16-row b128 read phases are 2-way (the pigeonhole floor for wide reads).
#define ATT_STRIDE 72
#define TILE_HW (64 * ATT_STRIDE)

static __device__ __forceinline__ float bf2f(u16 u) {
    union { float f; unsigned int i; } v; v.i = ((unsigned int)u) << 16; return v.f;
}
static __device__ __forceinline__ u16 f2bf(float f) {
    union { float f; unsigned int i; } v; v.f = f;
    unsigned int u = v.i;
    return (u16)((u + 0x7fffu + ((u >> 16) & 1u)) >> 16);   // RNE
}
static __device__ __forceinline__ float exp2_(float x) {
    return __builtin_exp2f(x);   // maps to v_exp_f32 (native 2^x)
}

static __device__ __forceinline__ f32x4 mfma16x16x32(bf16x8 a, bf16x8 b, f32x4 c) {
    return __builtin_amdgcn_mfma_f32_16x16x32_bf16(a, b, c, 0, 0, 0);
}

// async global->LDS, 16 B per lane (emits global_load_lds_dwordx4; m97 pattern).
typedef const __attribute__((address_space(1))) unsigned int* gas_u32;
typedef __attribute__((address_space(3))) unsigned int* las_u32;
static __device__ __forceinline__ void gload_lds16(const u16* g, u16* l) {
    __builtin_amdgcn_global_load_lds((gas_u32)g, (las_u32)l, 16, 0, 0);
}

// ---------------- merged prep: x cast + Wqkv transpose-cast + Wout transpose-cast ----------------
// One dispatch instead of three (fewer launch gaps; independent memory-bound sections).
// blocks [0,2048): cast x (8 elems/thread); [2048,5120): Wqkv^T; [5120,6144): Wout^T.
static __device__ __forceinline__ void tcast_body(const float* __restrict__ src,
                                                  u16* __restrict__ dst,
                                                  int R, int C, int c0, int r0,
                                                  u16 (*tile)[33]) {
    int tx = threadIdx.x & 31, ty = threadIdx.x >> 5;   // 32 x 8
#pragma unroll
    for (int i = 0; i < 32; i += 8)
        tile[ty + i][tx] = f2bf(src[(size_t)(r0 + ty + i) * C + c0 + tx]);
    __syncthreads();
#pragma unroll
    for (int i = 0; i < 32; i += 8)
        dst[(size_t)(c0 + ty + i) * R + r0 + tx] = tile[tx][ty + i];
}

__global__ __launch_bounds__(256) void k_prep(const float* __restrict__ x,
                                              u16* __restrict__ xb,
                                              const float* __restrict__ Wqkv,
                                              u16* __restrict__ wqkvt,
                                              const float* __restrict__ Wout,
                                              u16* __restrict__ woutt) {
    __shared__ u16 tile[32][33];
    int id = blockIdx.x;
    if (id < 2048) {
        int i = id * 256 + threadIdx.x;     // 524288 threads exactly cover 4096*1024/8
        const float4* s = (const float4*)(x + (size_t)i * 8);
        float4 a = s[0], b = s[1];
        u16 o[8] = { f2bf(a.x), f2bf(a.y), f2bf(a.z), f2bf(a.w),
                     f2bf(b.x), f2bf(b.y), f2bf(b.z), f2bf(b.w) };
        *(uint4*)(xb + (size_t)i * 8) = *(uint4*)o;
    } else if (id < 5120) {
        int local = id - 2048;              // 96 x 32 tiles of Wqkv [1024][3072]
        tcast_body(Wqkv, wqkvt, 1024, 3072, (local % 96) * 32, (local / 96) * 32, tile);
    } else {
        int local = id - 5120;              // 32 x 32 tiles of Wout [1024][1024]
        tcast_body(Wout, woutt, 1024, 1024, (local % 32) * 32, (local / 32) * 32, tile);
    }
}

// ------- GEMM: C[M][N] = A[M][K] @ Bt[N][K]^T + bias[N]; A,Bt bf16; bias fp32.
//   2-phase double-buffered pipeline (R8): stage tile t+1 via global_load_lds BEFORE
//   computing tile t, one barrier per K-step. BN = 128 for BOTH GEMMs (R13's BN=64
//   retile regressed -6..-9 us: 1.5x staging DMA + halved B-reuse; retired).
//   T1 XCD-aware tile swizzle (R12): hw id -> logical tile via sw=(id%8)*(nwg/8)+id/8
//   (bijective; nwg%8==0 for both launches) — A-panels stay L2-resident per XCD.
//   R14: FUSE_VT isolated — GEMM1 blocks with n0 >= 2C write the V third TRANSPOSED
//   directly to vt[col-2C][row] (4 consecutive rows/lane = one uint2, 32-B segments;
//   semantics harness-proven in R9/R13). Deletes the k_transpose_v dispatch and
//   ~17 MB of HBM round-trip (qkv V-write + transpose re-read). -------
template <typename OutT, bool FUSE_VT>
__global__ __launch_bounds__(256) void k_gemm_bt(const u16* __restrict__ A,
                                                 const u16* __restrict__ Bt,
                                                 const float* __restrict__ bias,
                                                 OutT* __restrict__ Cmat,
                                                 u16* __restrict__ vt,
                                                 int M, int N, int K) {
    __shared__ alignas(16) u16 As[2][128 * 32];
    __shared__ alignas(16) u16 Bs[2][128 * 32];
    int t = threadIdx.x;

    int nwg = gridDim.x * gridDim.y;
    int id = blockIdx.x + gridDim.x * blockIdx.y;
    int cpx = nwg >> 3;
    int sw = (id & 7) * cpx + (id >> 3);        // XCD-chunked, bijective
    int bx = sw % gridDim.x, by = sw / gridDim.x;
    int n0 = bx * 128, m0 = by * 128;

    int l = t & 63, w = t >> 6;
    int wm = (w >> 1) * 64, wn = (w & 1) * 64;
    int lr = l & 15, lq = l >> 4;

    const f32x4 vzero = {0.f, 0.f, 0.f, 0.f};
    f32x4 acc[4][4];
#pragma unroll
    for (int mi = 0; mi < 4; mi++)
#pragma unroll
        for (int ni = 0; ni < 4; ni++) acc[mi][ni] = vzero;

    int ar = t >> 2;            // 0..63
    int ac = (t & 3) * 8;       // 0,8,16,24  -> LDS hw index ar*32+ac == t*8 (base+lane*16B)
    const u16* Ag = A + (size_t)(m0 + ar) * K + ac;
    const u16* Bg = Bt + (size_t)(n0 + ar) * K + ac;

    int nk = K >> 5;            // K/32 K-steps

    auto stage = [&](int kt, int bu) {
        int k0 = kt << 5;
        gload_lds16(Ag + k0,                  &As[bu][t * 8]);
        gload_lds16(Ag + (size_t)64 * K + k0, &As[bu][t * 8 + 64 * 32]);
        gload_lds16(Bg + k0,                  &Bs[bu][t * 8]);
        gload_lds16(Bg + (size_t)64 * K + k0, &Bs[bu][t * 8 + 64 * 32]);
    };

    stage(0, 0);
    __syncthreads();

    int bu = 0;
    for (int kt = 0; kt < nk; ++kt) {
        if (kt + 1 < nk) stage(kt + 1, bu ^ 1);   // DMA overlaps this tile's compute

        bf16x8 af[4], bfr[4];
#pragma unroll
        for (int mi = 0; mi < 4; mi++)
            af[mi] = *(const bf16x8*)&As[bu][(wm + mi * 16 + lr) * 32 + lq * 8];
#pragma unroll
        for (int ni = 0; ni < 4; ni++)
            bfr[ni] = *(const bf16x8*)&Bs[bu][(wn + ni * 16 + lr) * 32 + lq * 8];
#pragma unroll
        for (int mi = 0; mi < 4; mi++)
#pragma unroll
            for (int ni = 0; ni < 4; ni++)
                acc[mi][ni] = mfma16x16x32(af[mi], bfr[ni], acc[mi][ni]);

        __syncthreads();
        bu ^= 1;
    }

    bool vpath = FUSE_VT && (n0 >= 2 * CDIM);   // block-uniform
    if (vpath) {
        // V third: write transposed to vt[(col-2C)][row]; 4 consecutive rows/lane -> uint2
#pragma unroll
        for (int ni = 0; ni < 4; ni++) {
            int col = n0 + wn + ni * 16 + lr;
            float bv = bias[col];
            int d = col - 2 * CDIM;             // vt row (h*HD + d)
#pragma unroll
            for (int mi = 0; mi < 4; mi++) {
                int row = m0 + wm + mi * 16 + lq * 4;
                union { u16 hh[4]; uint2 u2; } eo;
#pragma unroll
                for (int r = 0; r < 4; r++) eo.hh[r] = f2bf(acc[mi][ni][r] + bv);
                *(uint2*)&vt[(size_t)d * L_SEQ + row] = eo.u2;
            }
        }
    } else {
#pragma unroll
        for (int ni = 0; ni < 4; ni++) {
            int col = n0 + wn + ni * 16 + lr;
            float bv = bias[col];
#pragma unroll
            for (int mi = 0; mi < 4; mi++) {
                int row = m0 + wm + mi * 16 + lq * 4;
#pragma unroll
                for (int r = 0; r < 4; r++) {
                    float v = acc[mi][ni][r] + bv;
                    if constexpr (sizeof(OutT) == 2)
                        Cmat[(size_t)(row + r) * N + col] = f2bf(v);
                    else
                        Cmat[(size_t)(row + r) * N + col] = v;
                }
            }
        }
    }
}

// ---------------- causal flash attention: S^T formulation + paired q-tiles +
//   intra-block 2-way KV split (8 waves) + LDS double-buffer (1 barrier/iter) +
//   dist-2 register prefetch + shuffle-free common-path softmax (exp2 domain) +
//   XCD-local grid.  [UNCHANGED from the R12 216.2-us passing build] ----------------
// grid: (NH heads, 32 pairs), 512 threads. linear id = h + 16*pair -> XCD = h&7:
// all 32 blocks of a head share one XCD L2 (K/V = 1 MB/head fits 4 MB L2).
__global__ __launch_bounds__(512, 4) void k_attn(const u16* __restrict__ qkv,
                                                 const u16* __restrict__ vt,
                                                 u16* __restrict__ attn) {
    __shared__ alignas(16) u16 Ks[2][2 * TILE_HW];   // [group][buf][key][d]
    __shared__ alignas(16) u16 Vs[2][2 * TILE_HW];   // [group][buf][d][key]  (V^T)

    int t = threadIdx.x;
    int l = t & 63, w = t >> 6;       // w: 0..7
    int g = w >> 2;                   // KV-split group (0/1)
    int ww = w & 3;                   // wave within group
    int h = blockIdx.x;               // head (XCD-local)
    int pair = blockIdx.y;
    int lr = l & 15, lq = l >> 4;
    int tg = t & 255;                 // thread within group
    int row8 = tg >> 3;               // 0..31
    int ch = (tg & 7) * 8;            // 0..56
    int qloc = ww * 16 + lr;          // q within tile, this lane

    const f32x4 vzero = {0.f, 0.f, 0.f, 0.f};
    const u16* Kbase = qkv + (size_t)row8 * N_QKV + CDIM + h * HD + ch;   // + k0*N_QKV
    const u16* Vbase = vt + (size_t)(h * HD + row8) * L_SEQ + ch;         // + k0
    u16* KsG = Ks[g];
    u16* VsG = Vs[g];

#pragma unroll
    for (int phase = 0; phase < 2; phase++) {
        int tile = phase ? (63 - pair) : pair;
        int q0 = tile * 64;
        int nkv = tile + 1;
        int h0 = (nkv + 1) >> 1;              // uniform loop count (group 0's share)
        int myBeg = g ? h0 : 0;
        int myCnt = g ? (nkv - h0) : h0;

        // Q as B-operand frags: B[k=lq*8+j][n=lr], pre-scaled by log2e/8 (exp2 domain)
        const float SC = 0.125f * 1.44269504089f;
        bf16x8 bq[2];
        {
            const u16* Qg = qkv + (size_t)(q0 + qloc) * N_QKV + h * HD + lq * 8;
            union { uint4 u; u16 hh[8]; } q0u, q1u;
            q0u.u = *(const uint4*)(Qg);
            q1u.u = *(const uint4*)(Qg + 32);
            union { bf16x8 v; __bf16 e[8]; } f0, f1;
#pragma unroll
            for (int j = 0; j < 8; j++) {
                f0.e[j] = (__bf16)(bf2f(q0u.hh[j]) * SC);
                f1.e[j] = (__bf16)(bf2f(q1u.hh[j]) * SC);
            }
            bq[0] = f0.v; bq[1] = f1.v;
        }

        f32x4 o[4];                       // O^T[d][q]: col=q=lr, row(dt)=lq*4+r
#pragma unroll
        for (int dt = 0; dt < 4; dt++) o[dt] = vzero;
        float m_i = -1e30f, l_i = 0.f;    // l_i is LANE-PARTIAL (reduced once per phase)

        // prologue: stage tile 0 into buf0, prefetch tile 1 into regs
        uint4 rk0 = {0,0,0,0}, rk1 = {0,0,0,0}, rv0 = {0,0,0,0}, rv1 = {0,0,0,0};
        if (myCnt > 0) {
            const u16* Kg = Kbase + (size_t)(myBeg * 64) * N_QKV;
            rk0 = *(const uint4*)Kg;
            rk1 = *(const uint4*)(Kg + (size_t)32 * N_QKV);
            const u16* Vg = Vbase + myBeg * 64;
            rv0 = *(const uint4*)Vg;
            rv1 = *(const uint4*)(Vg + (size_t)32 * L_SEQ);
            *(uint4*)&KsG[row8 * ATT_STRIDE + ch]        = rk0;
            *(uint4*)&KsG[(row8 + 32) * ATT_STRIDE + ch] = rk1;
            *(uint4*)&VsG[row8 * ATT_STRIDE + ch]        = rv0;
            *(uint4*)&VsG[(row8 + 32) * ATT_STRIDE + ch] = rv1;
            if (myCnt > 1) {
                int k1 = (myBeg + 1) * 64;
                Kg = Kbase + (size_t)k1 * N_QKV;
                rk0 = *(const uint4*)Kg;
                rk1 = *(const uint4*)(Kg + (size_t)32 * N_QKV);
                Vg = Vbase + k1;
                rv0 = *(const uint4*)Vg;
                rv1 = *(const uint4*)(Vg + (size_t)32 * L_SEQ);
            }
        }
        __syncthreads();

        for (int j = 0; j < h0; ++j) {
            int cur = (j & 1) ? TILE_HW : 0;
            // stage next tile (regs loaded at j-1) into the other buffer
            if (j + 1 < myCnt) {
                int nxt = TILE_HW - cur;
                *(uint4*)&KsG[nxt + row8 * ATT_STRIDE + ch]        = rk0;
                *(uint4*)&KsG[nxt + (row8 + 32) * ATT_STRIDE + ch] = rk1;
                *(uint4*)&VsG[nxt + row8 * ATT_STRIDE + ch]        = rv0;
                *(uint4*)&VsG[nxt + (row8 + 32) * ATT_STRIDE + ch] = rv1;
            }
            // prefetch tile j+2 into regs (hidden under this iter's compute)
            if (j + 2 < myCnt) {
                int k1 = (myBeg + j + 2) * 64;
                const u16* Kg = Kbase + (size_t)k1 * N_QKV;
                rk0 = *(const uint4*)Kg;
                rk1 = *(const uint4*)(Kg + (size_t)32 * N_QKV);
                const u16* Vg = Vbase + k1;
                rv0 = *(const uint4*)Vg;
                rv1 = *(const uint4*)(Vg + (size_t)32 * L_SEQ);
            }

            if (j < myCnt) {
                const u16* Kc = KsG + cur;
                const u16* Vc = VsG + cur;

                // S^T = K Q^T: C-layout row = key = nt*16 + lq*4 + r, col = q = lr.
                f32x4 s[4];
#pragma unroll
                for (int nt = 0; nt < 4; nt++) s[nt] = vzero;
                __builtin_amdgcn_s_setprio(1);
#pragma unroll
                for (int ks = 0; ks < 2; ks++)
#pragma unroll
                    for (int nt = 0; nt < 4; nt++) {
                        bf16x8 ak = *(const bf16x8*)&Kc[(nt * 16 + lr) * ATT_STRIDE + ks * 32 + lq * 8];
                        s[nt] = mfma16x16x32(ak, bq[ks], s[nt]);
                    }
                __builtin_amdgcn_s_setprio(0);

                bool diag = (((myBeg + j) * 64) == q0);
                float tmax = -1e30f;
                if (diag) {
#pragma unroll
                    for (int nt = 0; nt < 4; nt++)
#pragma unroll
                        for (int r = 0; r < 4; r++) {
                            float v = s[nt][r];
                            if (nt * 16 + lq * 4 + r > qloc) v = -1e30f;
                            s[nt][r] = v;
                            tmax = fmaxf(tmax, v);
                        }
                } else {
#pragma unroll
                    for (int nt = 0; nt < 4; nt++)
#pragma unroll
                        for (int r = 0; r < 4; r++) tmax = fmaxf(tmax, s[nt][r]);
                }

                // defer-max (T13, log2 units THR=11): common path has NO cross-lane ops.
                if (!__all(tmax <= m_i + 11.0f)) {
                    float tq = fmaxf(tmax, __shfl_xor(tmax, 16));
                    tq = fmaxf(tq, __shfl_xor(tq, 32));
                    float mnew = fmaxf(m_i, tq);
                    float alpha = exp2_(m_i - mnew);
                    l_i *= alpha;
#pragma unroll
                    for (int dt = 0; dt < 4; dt++)
#pragma unroll
                        for (int r = 0; r < 4; r++) o[dt][r] *= alpha;
                    m_i = mnew;
                }

#pragma unroll
                for (int nt = 0; nt < 4; nt++)
#pragma unroll
                    for (int r = 0; r < 4; r++) {
                        float e = exp2_(s[nt][r] - m_i);   // p <= 2^11
                        s[nt][r] = e;
                        l_i += e;                          // lane-partial row-sum
                    }

                // PV: O^T[d][q] += V^T[d][key] * P^T[key][q]; two 16-key tiles per K=32 MFMA.
                __builtin_amdgcn_s_setprio(1);
#pragma unroll
                for (int a = 0; a < 2; a++) {
                    union { bf16x8 v; __bf16 e[8]; } bp;
#pragma unroll
                    for (int r = 0; r < 4; r++) {
                        bp.e[r]     = (__bf16)s[2 * a][r];
                        bp.e[r + 4] = (__bf16)s[2 * a + 1][r];
                    }
#pragma unroll
                    for (int dt = 0; dt < 4; dt++) {
                        union { bf16x8 v; uint2 u2[2]; } av;
                        const u16* vrow = &Vc[(dt * 16 + lr) * ATT_STRIDE + a * 32 + lq * 4];
                        av.u2[0] = *(const uint2*)(vrow);
                        av.u2[1] = *(const uint2*)(vrow + 16);
                        o[dt] = mfma16x16x32(av.v, bp.v, o[dt]);
                    }
                }
                __builtin_amdgcn_s_setprio(0);
            }
            __syncthreads();
        }

        // reduce deferred lane-partial row-sum (once per phase, off the hot loop)
        l_i += __shfl_xor(l_i, 16);
        l_i += __shfl_xor(l_i, 32);

        // ---- merge group partials via LDS (group 1 -> group 0), then epilogue ----
        // group 1's buffers are dead now; reuse as merge scratch.
        float* mb1 = (float*)Ks[1];   // per lane: m, l, o[0], o[1]  (10 f32)
        float* mb2 = (float*)Vs[1];   // per lane: o[2], o[3]        (8 f32)
        if (g == 1) {
            float* p = mb1 + tg * 10;
            p[0] = m_i; p[1] = l_i;
#pragma unroll
            for (int r = 0; r < 4; r++) { p[2 + r] = o[0][r]; p[6 + r] = o[1][r]; }
            float* p2 = mb2 + tg * 8;
#pragma unroll
            for (int r = 0; r < 4; r++) { p2[r] = o[2][r]; p2[4 + r] = o[3][r]; }
        }
        __syncthreads();
        if (g == 0) {
            float* p = mb1 + tg * 10;
            float m1v = p[0], l1v = p[1];
            float mnew = fmaxf(m_i, m1v);
            float a0 = exp2_(m_i - mnew);
            float a1 = exp2_(m1v - mnew);
            float lm = l_i * a0 + l1v * a1;
            float* p2 = mb2 + tg * 8;
            f32x4 o1[4];
#pragma unroll
            for (int r = 0; r < 4; r++) {
                o1[0][r] = p[2 + r]; o1[1][r] = p[6 + r];
                o1[2][r] = p2[r];    o1[3][r] = p2[4 + r];
            }
            float inv = 1.0f / lm;
            int qg = q0 + qloc;
#pragma unroll
            for (int dt = 0; dt < 4; dt++) {
                union { u16 hh[4]; uint2 u2; __bf16 e[4]; } eo;
#pragma unroll
                for (int r = 0; r < 4; r++)
                    eo.e[r] = (__bf16)((o[dt][r] * a0 + o1[dt][r] * a1) * inv);
                *(uint2*)&attn[(size_t)qg * CDIM + h * HD + dt * 16 + lq * 4] = eo.u2;
            }
        }
        __syncthreads();   // protect merge scratch before next phase's staging
    }
}

extern "C" void kernel_launch(void* const* d_in, const int* in_sizes, int n_in,
                              void* d_out, int out_size, void* d_ws, size_t ws_size,
                              hipStream_t stream) {
    const float* x    = (const float*)d_in[0];   // [4096][1024] fp32
    const float* Wqkv = (const float*)d_in[1];   // [1024][3072] fp32
    const float* bqkv = (const float*)d_in[2];   // [3072] fp32
    const float* Wout = (const float*)d_in[3];   // [1024][1024] fp32
    const float* bout = (const float*)d_in[4];   // [1024] fp32
    float* out = (float*)d_out;                  // [4096][1024] fp32

    char* ws = (char*)d_ws;
    u16* qkv   = (u16*)(ws);                     // [0, 25165824)
    u16* xb    = (u16*)(ws + 25165824);          // [25165824, 33554432) — aliases attn
    u16* attn  = xb;                             // xb dead after GEMM1
    u16* vt    = (u16*)(ws + 33554432);          // [33554432, 41943040)
    u16* wqkvt = (u16*)(ws + 41943040);          // [41943040, 48234496)
    u16* woutt = (u16*)(ws + 48234496);          // [48234496, 50331648)

    // 1. merged ingest: x -> bf16; Wqkv, Wout -> B^T bf16 (one dispatch)
    k_prep<<<dim3(6144), 256, 0, stream>>>(x, xb, Wqkv, wqkvt, Wout, woutt);
    // 2. qkv = x @ Wqkv + bqkv (bf16 out; XCD-swizzled tiles); V third -> vt directly
    k_gemm_bt<u16, true><<<dim3(24, 32), 256, 0, stream>>>(
        xb, wqkvt, bqkv, qkv, vt, 4096, 3072, 1024);
    // 3. causal flash attention (grid = (head, pair) so head -> fixed XCD for K/V L2 reuse)
    k_attn<<<dim3(16, 32), 512, 0, stream>>>(qkv, vt, attn);
    // 4. out = attn @ Wout + bout (fp32 out; XCD-swizzled; BN=128 as in R12)
    k_gemm_bt<float, false><<<dim3(8, 32), 256, 0, stream>>>(
        attn, woutt, bout, out, nullptr, 4096, 1024, 1024);
}

// Round 16
// 215.035 us; speedup vs baseline: 1.0713x; 1.0713x over previous
//
#include <hip/hip_runtime.h>
#include <hip/hip_bf16.h>

typedef unsigned short u16;
typedef __bf16 bf16x8 __attribute__((ext_vector_type(8)));
typedef float f32x4 __attribute__((ext_vector_type(4)));

#define L_SEQ 4096
#define CDIM  1024
#define NH    16
#define HD    64
#define N_QKV 3072
// LDS row stride (halfwords). 72 hw = 144 B: 16-B aligned rows; 36 dw = 4 mod 32
// -> 16-row b128 read phases are 2-way (the pigeonhole floor for wide reads).
#define ATT_STRIDE 72
#define TILE_HW (64 * ATT_STRIDE)

static __device__ __forceinline__ float bf2f(u16 u) {
    union { float f; unsigned int i; } v; v.i = ((unsigned int)u) << 16; return v.f;
}
static __device__ __forceinline__ u16 f2bf(float f) {
    union { float f; unsigned int i; } v; v.f = f;
    unsigned int u = v.i;
    return (u16)((u + 0x7fffu + ((u >> 16) & 1u)) >> 16);   // RNE
}
static __device__ __forceinline__ float exp2_(float x) {
    return __builtin_exp2f(x);   // maps to v_exp_f32 (native 2^x)
}

static __device__ __forceinline__ f32x4 mfma16x16x32(bf16x8 a, bf16x8 b, f32x4 c) {
    return __builtin_amdgcn_mfma_f32_16x16x32_bf16(a, b, c, 0, 0, 0);
}

// async global->LDS, 16 B per lane (emits global_load_lds_dwordx4; m97 pattern).
typedef const __attribute__((address_space(1))) unsigned int* gas_u32;
typedef __attribute__((address_space(3))) unsigned int* las_u32;
static __device__ __forceinline__ void gload_lds16(const u16* g, u16* l) {
    __builtin_amdgcn_global_load_lds((gas_u32)g, (las_u32)l, 16, 0, 0);
}

// ---------------- merged prep: x cast + Wqkv transpose-cast + Wout transpose-cast ----------------
// One dispatch instead of three (fewer launch gaps; independent memory-bound sections).
// blocks [0,2048): cast x (8 elems/thread); [2048,5120): Wqkv^T; [5120,6144): Wout^T.
static __device__ __forceinline__ void tcast_body(const float* __restrict__ src,
                                                  u16* __restrict__ dst,
                                                  int R, int C, int c0, int r0,
                                                  u16 (*tile)[33]) {
    int tx = threadIdx.x & 31, ty = threadIdx.x >> 5;   // 32 x 8
#pragma unroll
    for (int i = 0; i < 32; i += 8)
        tile[ty + i][tx] = f2bf(src[(size_t)(r0 + ty + i) * C + c0 + tx]);
    __syncthreads();
#pragma unroll
    for (int i = 0; i < 32; i += 8)
        dst[(size_t)(c0 + ty + i) * R + r0 + tx] = tile[tx][ty + i];
}

__global__ __launch_bounds__(256) void k_prep(const float* __restrict__ x,
                                              u16* __restrict__ xb,
                                              const float* __restrict__ Wqkv,
                                              u16* __restrict__ wqkvt,
                                              const float* __restrict__ Wout,
                                              u16* __restrict__ woutt) {
    __shared__ u16 tile[32][33];
    int id = blockIdx.x;
    if (id < 2048) {
        int i = id * 256 + threadIdx.x;     // 524288 threads exactly cover 4096*1024/8
        const float4* s = (const float4*)(x + (size_t)i * 8);
        float4 a = s[0], b = s[1];
        u16 o[8] = { f2bf(a.x), f2bf(a.y), f2bf(a.z), f2bf(a.w),
                     f2bf(b.x), f2bf(b.y), f2bf(b.z), f2bf(b.w) };
        *(uint4*)(xb + (size_t)i * 8) = *(uint4*)o;
    } else if (id < 5120) {
        int local = id - 2048;              // 96 x 32 tiles of Wqkv [1024][3072]
        tcast_body(Wqkv, wqkvt, 1024, 3072, (local % 96) * 32, (local / 96) * 32, tile);
    } else {
        int local = id - 5120;              // 32 x 32 tiles of Wout [1024][1024]
        tcast_body(Wout, woutt, 1024, 1024, (local % 32) * 32, (local / 32) * 32, tile);
    }
}

// ---------------- V transpose (bf16): qkv[:, 2C + h*64 + d] -> vt[h*64+d][key] ----------------
__global__ __launch_bounds__(256) void k_transpose_v(const u16* __restrict__ qkv,
                                                     u16* __restrict__ vt) {
    __shared__ u16 tile[32][33];
    int k0 = blockIdx.x * 32, d0 = blockIdx.y * 32, h = blockIdx.z;
    int tx = threadIdx.x & 31, ty = threadIdx.x >> 5;
#pragma unroll
    for (int i = 0; i < 32; i += 8)
        tile[ty + i][tx] = qkv[(size_t)(k0 + ty + i) * N_QKV + 2 * CDIM + h * HD + d0 + tx];
    __syncthreads();
#pragma unroll
    for (int i = 0; i < 32; i += 8)
        vt[(size_t)(h * HD + d0 + ty + i) * L_SEQ + k0 + tx] = tile[tx][ty + i];
}

// ------- GEMM: C[M][N] = A[M][K] @ Bt[N][K]^T + bias[N]; A,Bt bf16; bias fp32.
//   2-phase double-buffered pipeline (R8): stage tile t+1 via global_load_lds BEFORE
//   computing tile t, one barrier per K-step.
//   T1 XCD-aware tile swizzle (R12): hw id -> logical tile via sw=(id%8)*(nwg/8)+id/8
//   (bijective; nwg%8==0 for both launches) — A-panels stay L2-resident per XCD.
//   [FINAL = R12 config. Retired by measurement: operand-swap epilogue (-17us, R6),
//    BN=64 retile (-6..-9us, R13), FUSE_VT (-14us, R15), forced 8-wave occupancy
//    (VGPR clamp -> 304 MB spills, R10).] -------
template <typename OutT>
__global__ __launch_bounds__(256) void k_gemm_bt(const u16* __restrict__ A,
                                                 const u16* __restrict__ Bt,
                                                 const float* __restrict__ bias,
                                                 OutT* __restrict__ Cmat,
                                                 int M, int N, int K) {
    __shared__ alignas(16) u16 As[2][128 * 32];
    __shared__ alignas(16) u16 Bs[2][128 * 32];
    int t = threadIdx.x;

    int nwg = gridDim.x * gridDim.y;
    int id = blockIdx.x + gridDim.x * blockIdx.y;
    int cpx = nwg >> 3;
    int sw = (id & 7) * cpx + (id >> 3);        // XCD-chunked, bijective
    int bx = sw % gridDim.x, by = sw / gridDim.x;
    int n0 = bx * 128, m0 = by * 128;

    int l = t & 63, w = t >> 6;
    int wm = (w >> 1) * 64, wn = (w & 1) * 64;
    int lr = l & 15, lq = l >> 4;

    const f32x4 vzero = {0.f, 0.f, 0.f, 0.f};
    f32x4 acc[4][4];
#pragma unroll
    for (int mi = 0; mi < 4; mi++)
#pragma unroll
        for (int ni = 0; ni < 4; ni++) acc[mi][ni] = vzero;

    int ar = t >> 2;            // 0..63
    int ac = (t & 3) * 8;       // 0,8,16,24  -> LDS hw index ar*32+ac == t*8 (base+lane*16B)
    const u16* Ag = A + (size_t)(m0 + ar) * K + ac;
    const u16* Bg = Bt + (size_t)(n0 + ar) * K + ac;

    int nk = K >> 5;            // K/32 K-steps

    auto stage = [&](int kt, int bu) {
        int k0 = kt << 5;
        gload_lds16(Ag + k0,                  &As[bu][t * 8]);
        gload_lds16(Ag + (size_t)64 * K + k0, &As[bu][t * 8 + 64 * 32]);
        gload_lds16(Bg + k0,                  &Bs[bu][t * 8]);
        gload_lds16(Bg + (size_t)64 * K + k0, &Bs[bu][t * 8 + 64 * 32]);
    };

    stage(0, 0);
    __syncthreads();

    int bu = 0;
    for (int kt = 0; kt < nk; ++kt) {
        if (kt + 1 < nk) stage(kt + 1, bu ^ 1);   // DMA overlaps this tile's compute

        bf16x8 af[4], bfr[4];
#pragma unroll
        for (int mi = 0; mi < 4; mi++)
            af[mi] = *(const bf16x8*)&As[bu][(wm + mi * 16 + lr) * 32 + lq * 8];
#pragma unroll
        for (int ni = 0; ni < 4; ni++)
            bfr[ni] = *(const bf16x8*)&Bs[bu][(wn + ni * 16 + lr) * 32 + lq * 8];
#pragma unroll
        for (int mi = 0; mi < 4; mi++)
#pragma unroll
            for (int ni = 0; ni < 4; ni++)
                acc[mi][ni] = mfma16x16x32(af[mi], bfr[ni], acc[mi][ni]);

        __syncthreads();
        bu ^= 1;
    }

#pragma unroll
    for (int ni = 0; ni < 4; ni++) {
        int col = n0 + wn + ni * 16 + lr;
        float bv = bias[col];
#pragma unroll
        for (int mi = 0; mi < 4; mi++) {
            int row = m0 + wm + mi * 16 + lq * 4;
#pragma unroll
            for (int r = 0; r < 4; r++) {
                float v = acc[mi][ni][r] + bv;
                if constexpr (sizeof(OutT) == 2)
                    Cmat[(size_t)(row + r) * N + col] = f2bf(v);
                else
                    Cmat[(size_t)(row + r) * N + col] = v;
            }
        }
    }
}

// ---------------- causal flash attention: S^T formulation + paired q-tiles +
//   intra-block 2-way KV split (8 waves) + LDS double-buffer (1 barrier/iter) +
//   dist-2 register prefetch + shuffle-free common-path softmax (exp2 domain) +
//   XCD-local grid.  [FINAL: this structure held ~85us against 5 structural attacks]
// grid: (NH heads, 32 pairs), 512 threads. linear id = h + 16*pair -> XCD = h&7:
// all 32 blocks of a head share one XCD L2 (K/V = 1 MB/head fits 4 MB L2).
__global__ __launch_bounds__(512, 4) void k_attn(const u16* __restrict__ qkv,
                                                 const u16* __restrict__ vt,
                                                 u16* __restrict__ attn) {
    __shared__ alignas(16) u16 Ks[2][2 * TILE_HW];   // [group][buf][key][d]
    __shared__ alignas(16) u16 Vs[2][2 * TILE_HW];   // [group][buf][d][key]  (V^T)

    int t = threadIdx.x;
    int l = t & 63, w = t >> 6;       // w: 0..7
    int g = w >> 2;                   // KV-split group (0/1)
    int ww = w & 3;                   // wave within group
    int h = blockIdx.x;               // head (XCD-local)
    int pair = blockIdx.y;
    int lr = l & 15, lq = l >> 4;
    int tg = t & 255;                 // thread within group
    int row8 = tg >> 3;               // 0..31
    int ch = (tg & 7) * 8;            // 0..56
    int qloc = ww * 16 + lr;          // q within tile, this lane

    const f32x4 vzero = {0.f, 0.f, 0.f, 0.f};
    const u16* Kbase = qkv + (size_t)row8 * N_QKV + CDIM + h * HD + ch;   // + k0*N_QKV
    const u16* Vbase = vt + (size_t)(h * HD + row8) * L_SEQ + ch;         // + k0
    u16* KsG = Ks[g];
    u16* VsG = Vs[g];

#pragma unroll
    for (int phase = 0; phase < 2; phase++) {
        int tile = phase ? (63 - pair) : pair;
        int q0 = tile * 64;
        int nkv = tile + 1;
        int h0 = (nkv + 1) >> 1;              // uniform loop count (group 0's share)
        int myBeg = g ? h0 : 0;
        int myCnt = g ? (nkv - h0) : h0;

        // Q as B-operand frags: B[k=lq*8+j][n=lr], pre-scaled by log2e/8 (exp2 domain)
        const float SC = 0.125f * 1.44269504089f;
        bf16x8 bq[2];
        {
            const u16* Qg = qkv + (size_t)(q0 + qloc) * N_QKV + h * HD + lq * 8;
            union { uint4 u; u16 hh[8]; } q0u, q1u;
            q0u.u = *(const uint4*)(Qg);
            q1u.u = *(const uint4*)(Qg + 32);
            union { bf16x8 v; __bf16 e[8]; } f0, f1;
#pragma unroll
            for (int j = 0; j < 8; j++) {
                f0.e[j] = (__bf16)(bf2f(q0u.hh[j]) * SC);
                f1.e[j] = (__bf16)(bf2f(q1u.hh[j]) * SC);
            }
            bq[0] = f0.v; bq[1] = f1.v;
        }

        f32x4 o[4];                       // O^T[d][q]: col=q=lr, row(dt)=lq*4+r
#pragma unroll
        for (int dt = 0; dt < 4; dt++) o[dt] = vzero;
        float m_i = -1e30f, l_i = 0.f;    // l_i is LANE-PARTIAL (reduced once per phase)

        // prologue: stage tile 0 into buf0, prefetch tile 1 into regs
        uint4 rk0 = {0,0,0,0}, rk1 = {0,0,0,0}, rv0 = {0,0,0,0}, rv1 = {0,0,0,0};
        if (myCnt > 0) {
            const u16* Kg = Kbase + (size_t)(myBeg * 64) * N_QKV;
            rk0 = *(const uint4*)Kg;
            rk1 = *(const uint4*)(Kg + (size_t)32 * N_QKV);
            const u16* Vg = Vbase + myBeg * 64;
            rv0 = *(const uint4*)Vg;
            rv1 = *(const uint4*)(Vg + (size_t)32 * L_SEQ);
            *(uint4*)&KsG[row8 * ATT_STRIDE + ch]        = rk0;
            *(uint4*)&KsG[(row8 + 32) * ATT_STRIDE + ch] = rk1;
            *(uint4*)&VsG[row8 * ATT_STRIDE + ch]        = rv0;
            *(uint4*)&VsG[(row8 + 32) * ATT_STRIDE + ch] = rv1;
            if (myCnt > 1) {
                int k1 = (myBeg + 1) * 64;
                Kg = Kbase + (size_t)k1 * N_QKV;
                rk0 = *(const uint4*)Kg;
                rk1 = *(const uint4*)(Kg + (size_t)32 * N_QKV);
                Vg = Vbase + k1;
                rv0 = *(const uint4*)Vg;
                rv1 = *(const uint4*)(Vg + (size_t)32 * L_SEQ);
            }
        }
        __syncthreads();

        for (int j = 0; j < h0; ++j) {
            int cur = (j & 1) ? TILE_HW : 0;
            // stage next tile (regs loaded at j-1) into the other buffer
            if (j + 1 < myCnt) {
                int nxt = TILE_HW - cur;
                *(uint4*)&KsG[nxt + row8 * ATT_STRIDE + ch]        = rk0;
                *(uint4*)&KsG[nxt + (row8 + 32) * ATT_STRIDE + ch] = rk1;
                *(uint4*)&VsG[nxt + row8 * ATT_STRIDE + ch]        = rv0;
                *(uint4*)&VsG[nxt + (row8 + 32) * ATT_STRIDE + ch] = rv1;
            }
            // prefetch tile j+2 into regs (hidden under this iter's compute)
            if (j + 2 < myCnt) {
                int k1 = (myBeg + j + 2) * 64;
                const u16* Kg = Kbase + (size_t)k1 * N_QKV;
                rk0 = *(const uint4*)Kg;
                rk1 = *(const uint4*)(Kg + (size_t)32 * N_QKV);
                const u16* Vg = Vbase + k1;
                rv0 = *(const uint4*)Vg;
                rv1 = *(const uint4*)(Vg + (size_t)32 * L_SEQ);
            }

            if (j < myCnt) {
                const u16* Kc = KsG + cur;
                const u16* Vc = VsG + cur;

                // S^T = K Q^T: C-layout row = key = nt*16 + lq*4 + r, col = q = lr.
                f32x4 s[4];
#pragma unroll
                for (int nt = 0; nt < 4; nt++) s[nt] = vzero;
                __builtin_amdgcn_s_setprio(1);
#pragma unroll
                for (int ks = 0; ks < 2; ks++)
#pragma unroll
                    for (int nt = 0; nt < 4; nt++) {
                        bf16x8 ak = *(const bf16x8*)&Kc[(nt * 16 + lr) * ATT_STRIDE + ks * 32 + lq * 8];
                        s[nt] = mfma16x16x32(ak, bq[ks], s[nt]);
                    }
                __builtin_amdgcn_s_setprio(0);

                bool diag = (((myBeg + j) * 64) == q0);
                float tmax = -1e30f;
                if (diag) {
#pragma unroll
                    for (int nt = 0; nt < 4; nt++)
#pragma unroll
                        for (int r = 0; r < 4; r++) {
                            float v = s[nt][r];
                            if (nt * 16 + lq * 4 + r > qloc) v = -1e30f;
                            s[nt][r] = v;
                            tmax = fmaxf(tmax, v);
                        }
                } else {
#pragma unroll
                    for (int nt = 0; nt < 4; nt++)
#pragma unroll
                        for (int r = 0; r < 4; r++) tmax = fmaxf(tmax, s[nt][r]);
                }

                // defer-max (T13, log2 units THR=11): common path has NO cross-lane ops.
                if (!__all(tmax <= m_i + 11.0f)) {
                    float tq = fmaxf(tmax, __shfl_xor(tmax, 16));
                    tq = fmaxf(tq, __shfl_xor(tq, 32));
                    float mnew = fmaxf(m_i, tq);
                    float alpha = exp2_(m_i - mnew);
                    l_i *= alpha;
#pragma unroll
                    for (int dt = 0; dt < 4; dt++)
#pragma unroll
                        for (int r = 0; r < 4; r++) o[dt][r] *= alpha;
                    m_i = mnew;
                }

#pragma unroll
                for (int nt = 0; nt < 4; nt++)
#pragma unroll
                    for (int r = 0; r < 4; r++) {
                        float e = exp2_(s[nt][r] - m_i);   // p <= 2^11
                        s[nt][r] = e;
                        l_i += e;                          // lane-partial row-sum
                    }

                // PV: O^T[d][q] += V^T[d][key] * P^T[key][q]; two 16-key tiles per K=32 MFMA.
                __builtin_amdgcn_s_setprio(1);
#pragma unroll
                for (int a = 0; a < 2; a++) {
                    union { bf16x8 v; __bf16 e[8]; } bp;
#pragma unroll
                    for (int r = 0; r < 4; r++) {
                        bp.e[r]     = (__bf16)s[2 * a][r];
                        bp.e[r + 4] = (__bf16)s[2 * a + 1][r];
                    }
#pragma unroll
                    for (int dt = 0; dt < 4; dt++) {
                        union { bf16x8 v; uint2 u2[2]; } av;
                        const u16* vrow = &Vc[(dt * 16 + lr) * ATT_STRIDE + a * 32 + lq * 4];
                        av.u2[0] = *(const uint2*)(vrow);
                        av.u2[1] = *(const uint2*)(vrow + 16);
                        o[dt] = mfma16x16x32(av.v, bp.v, o[dt]);
                    }
                }
                __builtin_amdgcn_s_setprio(0);
            }
            __syncthreads();
        }

        // reduce deferred lane-partial row-sum (once per phase, off the hot loop)
        l_i += __shfl_xor(l_i, 16);
        l_i += __shfl_xor(l_i, 32);

        // ---- merge group partials via LDS (group 1 -> group 0), then epilogue ----
        // group 1's buffers are dead now; reuse as merge scratch.
        float* mb1 = (float*)Ks[1];   // per lane: m, l, o[0], o[1]  (10 f32)
        float* mb2 = (float*)Vs[1];   // per lane: o[2], o[3]        (8 f32)
        if (g == 1) {
            float* p = mb1 + tg * 10;
            p[0] = m_i; p[1] = l_i;
#pragma unroll
            for (int r = 0; r < 4; r++) { p[2 + r] = o[0][r]; p[6 + r] = o[1][r]; }
            float* p2 = mb2 + tg * 8;
#pragma unroll
            for (int r = 0; r < 4; r++) { p2[r] = o[2][r]; p2[4 + r] = o[3][r]; }
        }
        __syncthreads();
        if (g == 0) {
            float* p = mb1 + tg * 10;
            float m1v = p[0], l1v = p[1];
            float mnew = fmaxf(m_i, m1v);
            float a0 = exp2_(m_i - mnew);
            float a1 = exp2_(m1v - mnew);
            float lm = l_i * a0 + l1v * a1;
            float* p2 = mb2 + tg * 8;
            f32x4 o1[4];
#pragma unroll
            for (int r = 0; r < 4; r++) {
                o1[0][r] = p[2 + r]; o1[1][r] = p[6 + r];
                o1[2][r] = p2[r];    o1[3][r] = p2[4 + r];
            }
            float inv = 1.0f / lm;
            int qg = q0 + qloc;
#pragma unroll
            for (int dt = 0; dt < 4; dt++) {
                union { u16 hh[4]; uint2 u2; __bf16 e[4]; } eo;
#pragma unroll
                for (int r = 0; r < 4; r++)
                    eo.e[r] = (__bf16)((o[dt][r] * a0 + o1[dt][r] * a1) * inv);
                *(uint2*)&attn[(size_t)qg * CDIM + h * HD + dt * 16 + lq * 4] = eo.u2;
            }
        }
        __syncthreads();   // protect merge scratch before next phase's staging
    }
}

extern "C" void kernel_launch(void* const* d_in, const int* in_sizes, int n_in,
                              void* d_out, int out_size, void* d_ws, size_t ws_size,
                              hipStream_t stream) {
    const float* x    = (const float*)d_in[0];   // [4096][1024] fp32
    const float* Wqkv = (const float*)d_in[1];   // [1024][3072] fp32
    const float* bqkv = (const float*)d_in[2];   // [3072] fp32
    const float* Wout = (const float*)d_in[3];   // [1024][1024] fp32
    const float* bout = (const float*)d_in[4];   // [1024] fp32
    float* out = (float*)d_out;                  // [4096][1024] fp32

    char* ws = (char*)d_ws;
    u16* qkv   = (u16*)(ws);                     // [0, 25165824)
    u16* xb    = (u16*)(ws + 25165824);          // [25165824, 33554432) — aliases attn
    u16* attn  = xb;                             // xb dead after GEMM1
    u16* vt    = (u16*)(ws + 33554432);          // [33554432, 41943040)
    u16* wqkvt = (u16*)(ws + 41943040);          // [41943040, 48234496)
    u16* woutt = (u16*)(ws + 48234496);          // [48234496, 50331648)

    // 1. merged ingest: x -> bf16; Wqkv, Wout -> B^T bf16 (one dispatch)
    k_prep<<<dim3(6144), 256, 0, stream>>>(x, xb, Wqkv, wqkvt, Wout, woutt);
    // 2. qkv = x @ Wqkv + bqkv   (bf16 out; XCD-swizzled tiles)
    k_gemm_bt<u16><<<dim3(24, 32), 256, 0, stream>>>(xb, wqkvt, bqkv, qkv, 4096, 3072, 1024);
    // 3. V^T per head
    k_transpose_v<<<dim3(128, 2, 16), 256, 0, stream>>>(qkv, vt);
    // 4. causal flash attention (grid = (head, pair) so head -> fixed XCD for K/V L2 reuse)
    k_attn<<<dim3(16, 32), 512, 0, stream>>>(qkv, vt, attn);
    // 5. out = attn @ Wout + bout   (fp32 out; XCD-swizzled tiles)
    k_gemm_bt<float><<<dim3(8, 32), 256, 0, stream>>>(attn, woutt, bout, out, 4096, 1024, 1024);
}